// Round 1
// baseline (523.074 us; speedup 1.0000x reference)
//
#include <hip/hip_runtime.h>
#include <cstdint>
#include <cstddef>

#define N_NODES 100000
#define N_EDGES 500000
#define IN_DIM  128
#define HID     512
#define N_CLS   40
#define N_SBLK  ((N_NODES + 255) / 256)   // 391 scan blocks
#define N_PREPB 352                       // prep blocks (W1F/W2F)
#define N_BUILD (N_SBLK + N_PREPB)        // 743 blocks — co-resident (<=1024 @ 4 blocks/CU)
#define BUILD_THREADS (N_BUILD * 256)     // 190208
#define XBF_TOTAL 3200000                 // float4 count of x

typedef short bf16x8 __attribute__((ext_vector_type(8)));
typedef float f32x4 __attribute__((ext_vector_type(4)));

__device__ inline unsigned short f2bf(float f) {
  unsigned u = __float_as_uint(f);
  u = u + 0x7fffu + ((u >> 16) & 1u);          // RNE
  return (unsigned short)(u >> 16);
}
__device__ inline float blo(unsigned u) { return __uint_as_float(u << 16); }
__device__ inline float bhi(unsigned u) { return __uint_as_float(u & 0xffff0000u); }

// ---------------- zero (cnt + flags incl. grid-sync counters) ----------------
__global__ __launch_bounds__(256) void k_zero(int* __restrict__ cnt, unsigned* __restrict__ flags) {
  int i = blockIdx.x * 256 + threadIdx.x;
  if (i < N_NODES) cnt[i] = 0;
  if (i < 1024) flags[i] = 0;                  // [0,391) lookback flags, [512],[513] phase counters
}

// ---------------- fused CSR build: count + xbf + scan/prep + fill ----------------
// All 743 blocks co-resident (4 waves, 1KB LDS, VGPR<=128 via launch_bounds(256,4) -> 4 blocks/CU).
// Grid syncs via device-scope atomic counters in flags[512]/flags[513]; normal-store hand-off
// across blocks (offsets/cursor/dinv -> phase 3) is fenced with __threadfence() (agent release:
// buffer_wbl2; acquire: buffer_inv) so non-coherent per-XCD L2s cannot serve stale data.
__global__ __launch_bounds__(256, 4) void k_build(const int* __restrict__ src, const int* __restrict__ dst,
                                                  int* __restrict__ cnt, unsigned* __restrict__ flags,
                                                  int* __restrict__ offsets, int* __restrict__ cursor,
                                                  float* __restrict__ dinv,
                                                  const float* __restrict__ x, uint2* __restrict__ xb2,
                                                  const float* __restrict__ W1, const float* __restrict__ W2,
                                                  unsigned short* __restrict__ W1F, unsigned short* __restrict__ W2F,
                                                  int2* __restrict__ epair) {
  __shared__ int s[256];
  __shared__ int base_sh;
  const int b = blockIdx.x, tid = threadIdx.x;
  const int gt = b * 256 + tid;

  // ---- phase 1: in-degree count (grid-stride, 3 iters) ----
  for (int e = gt; e < N_EDGES; e += BUILD_THREADS) atomicAdd(&cnt[dst[e]], 1);
  __threadfence();
  __syncthreads();
  if (tid == 0) atomicAdd(&flags[512], 1u);

  // ---- filler: x -> bf16 conversion (independent until k_gather1) ----
  for (int t = gt; t < XBF_TOTAL; t += BUILD_THREADS) {
    float4 v = ((const float4*)x)[t];
    uint2 o;
    o.x = (unsigned)f2bf(v.x) | ((unsigned)f2bf(v.y) << 16);
    o.y = (unsigned)f2bf(v.z) | ((unsigned)f2bf(v.w) << 16);
    xb2[t] = o;
  }

  if (tid == 0) { while (atomicAdd(&flags[512], 0u) < (unsigned)N_BUILD) __builtin_amdgcn_s_sleep(2); }
  __syncthreads();
  __threadfence();                              // acquire before normal reads of cnt

  // ---- phase 2: scan (decoupled lookback) + dinv | W1F/W2F prep ----
  if (b < N_SBLK) {
    int i = b * 256 + tid;
    int v = (i < N_NODES) ? cnt[i] : 0;
    s[tid] = v;
    __syncthreads();
    #pragma unroll
    for (int off = 1; off < 256; off <<= 1) {
      int t = (tid >= off) ? s[tid - off] : 0;
      __syncthreads();
      s[tid] += t;
      __syncthreads();
    }
    int incl = s[tid];
    if (tid == 0) {
      int total = s[255];
      if (b == 0) {
        atomicExch(&flags[0], (2u << 30) | (unsigned)total);
        base_sh = 0;
      } else {
        atomicExch(&flags[b], (1u << 30) | (unsigned)total);
        int base = 0, pred = b - 1;
        while (true) {
          unsigned f;
          do { f = atomicAdd(&flags[pred], 0u); } while ((f >> 30) == 0u);
          base += (int)(f & 0x3fffffffu);
          if ((f >> 30) == 2u) break;
          --pred;
        }
        atomicExch(&flags[b], (2u << 30) | (unsigned)(base + (unsigned)total));
        base_sh = base;
      }
    }
    __syncthreads();
    int gbase = base_sh;
    if (i < N_NODES) {
      int excl = gbase + incl - v;
      offsets[i] = excl;
      cursor[i]  = excl;
      dinv[i]    = rsqrtf((float)(v + 1));     // +1 self-loop
    }
    if (b == 0 && tid == 0) offsets[N_NODES] = N_EDGES;   // sentinel
  } else {
    int t = (b - N_SBLK) * 256 + tid;          // 90112 exact
    if (t < 65536) {
      int j = t & 7, lane = (t >> 3) & 63, rest = t >> 9;   // rest = c*4+s
      int s2 = rest & 3, c = rest >> 2;
      int k = s2 * 32 + (lane >> 4) * 8 + j;
      int n = c * 16 + (lane & 15);
      W1F[t] = f2bf(W1[k * HID + n]);
    } else {
      int u = t - 65536;                        // 24576
      int j = u & 7, lane = (u >> 3) & 63, rest = u >> 9;   // rest = gk*3+ct
      int ct = rest % 3, gk = rest / 3;
      int k = gk * 32 + (lane >> 4) * 8 + j;
      int col = ct * 16 + (lane & 15);
      W2F[u] = (col < N_CLS) ? f2bf(W2[k * N_CLS + col]) : (unsigned short)0;
    }
  }
  __threadfence();                              // release offsets/cursor/dinv (writeback L2)
  __syncthreads();
  if (tid == 0) {
    atomicAdd(&flags[513], 1u);
    while (atomicAdd(&flags[513], 0u) < (unsigned)N_BUILD) __builtin_amdgcn_s_sleep(2);
  }
  __syncthreads();
  __threadfence();                              // acquire before reading offsets/cursor/dinv

  // ---- phase 3: fill CSR with (src, norm) pairs (grid-stride) ----
  for (int e = gt; e < N_EDGES; e += BUILD_THREADS) {
    int ss = src[e], d = dst[e];
    int pos = atomicAdd(&cursor[d], 1);
    float nrm = dinv[ss] * dinv[d];
    epair[pos] = make_int2(ss, __float_as_int(nrm));
  }
}

// ---------------- layer-1 aggregation (gather, bf16): Z1 = Ahat @ X ----------------
// ONE node per 32-lane half (row = 32 x uint2 = 256B); 2 nodes/wave; 4-way unroll
// => 8 concurrent row chains per wave, no cross-lane reduction needed.
__global__ __launch_bounds__(256) void k_gather1(const uint2* __restrict__ xb, const int2* __restrict__ ep,
                                                 const int* __restrict__ offsets,
                                                 const float* __restrict__ dinv, uint2* __restrict__ z1) {
  int lane = threadIdx.x & 63, h = lane >> 5, l = lane & 31;
  int d = blockIdx.x * 8 + (threadIdx.x >> 6) * 2 + h;   // 12500 blocks x 8 = 100000 exact
  int start = offsets[d], end = offsets[d + 1];
  float dd = dinv[d], sl = dd * dd;
  uint2 su = xb[(size_t)d * 32 + l];
  float a0 = sl * blo(su.x), a1 = sl * bhi(su.x), a2 = sl * blo(su.y), a3 = sl * bhi(su.y);
  float p0a = 0.f, p1a = 0.f, p2a = 0.f, p3a = 0.f;
  float q0a = 0.f, q1a = 0.f, q2a = 0.f, q3a = 0.f;
  float r0a = 0.f, r1a = 0.f, r2a = 0.f, r3a = 0.f;

  int i = start;
  for (; i + 3 < end; i += 4) {
    int2 e0 = ep[i], e1 = ep[i + 1], e2 = ep[i + 2], e3 = ep[i + 3];
    uint2 r0 = xb[(size_t)e0.x * 32 + l];
    uint2 r1 = xb[(size_t)e1.x * 32 + l];
    uint2 r2 = xb[(size_t)e2.x * 32 + l];
    uint2 r3 = xb[(size_t)e3.x * 32 + l];
    float n0 = __int_as_float(e0.y), n1 = __int_as_float(e1.y);
    float n2 = __int_as_float(e2.y), n3 = __int_as_float(e3.y);
    a0  += n0 * blo(r0.x); a1  += n0 * bhi(r0.x); a2  += n0 * blo(r0.y); a3  += n0 * bhi(r0.y);
    p0a += n1 * blo(r1.x); p1a += n1 * bhi(r1.x); p2a += n1 * blo(r1.y); p3a += n1 * bhi(r1.y);
    q0a += n2 * blo(r2.x); q1a += n2 * bhi(r2.x); q2a += n2 * blo(r2.y); q3a += n2 * bhi(r2.y);
    r0a += n3 * blo(r3.x); r1a += n3 * bhi(r3.x); r2a += n3 * blo(r3.y); r3a += n3 * bhi(r3.y);
  }
  for (; i < end; ++i) {
    int2 e0 = ep[i];
    uint2 r0 = xb[(size_t)e0.x * 32 + l];
    float n0 = __int_as_float(e0.y);
    a0 += n0 * blo(r0.x); a1 += n0 * bhi(r0.x); a2 += n0 * blo(r0.y); a3 += n0 * bhi(r0.y);
  }
  a0 += p0a + q0a + r0a;
  a1 += p1a + q1a + r1a;
  a2 += p2a + q2a + r2a;
  a3 += p3a + q3a + r3a;
  uint2 o;
  o.x = (unsigned)f2bf(a0) | ((unsigned)f2bf(a1) << 16);
  o.y = (unsigned)f2bf(a2) | ((unsigned)f2bf(a3) << 16);
  z1[(size_t)d * 32 + l] = o;
}

// ---------------- fused GEMM1+bias+relu+GEMM2 via bf16 MFMA ----------------
// 1 wave per block, 64 rows (4 m-tiles): every B-fragment load feeds 16 MFMAs.
// 1563 blocks -> ~6.1 blocks/CU (better tail than 391x4-wave). No __syncthreads.
// Epilogue: pair-swap (shfl_xor 1) + v_cvt_pk_bf16_f32 -> b32 LDS stores
// (2 per t,nt instead of 4 u16 stores + 16 f2bf ops). Readback stays b128.
#define HS_STRIDE 56   // ushorts; 112B rows: 16B-aligned b128 reads, worst 2-way conflict = free
__global__ __launch_bounds__(64) void k_fused_mfma(const unsigned short* __restrict__ z1b,
                                                   const unsigned short* __restrict__ W1F,
                                                   const float* __restrict__ b1,
                                                   const unsigned short* __restrict__ W2F,
                                                   unsigned short* __restrict__ Pb) {
  __shared__ unsigned short Hs[64 * HS_STRIDE];   // 7168 B
  const int lane = threadIdx.x;                   // 0..63 (one wave)
  const int c16  = lane & 15, quad = lane >> 4;
  const int odd  = c16 & 1;
  const int mbase = blockIdx.x * 64;              // 1563 blocks x 64 >= 100000

  bf16x8 afrag[4][4];
  #pragma unroll
  for (int t = 0; t < 4; ++t) {
    int mrow = mbase + t * 16 + c16;
    int meff = (mrow < N_NODES) ? mrow : 0;
    const bf16x8* arow = (const bf16x8*)(z1b + (size_t)meff * IN_DIM + quad * 8);
    afrag[t][0] = arow[0];
    afrag[t][1] = arow[4];     // +32 ushorts
    afrag[t][2] = arow[8];
    afrag[t][3] = arow[12];
  }

  f32x4 pacc[4][3];
  #pragma unroll
  for (int t = 0; t < 4; ++t)
    #pragma unroll
    for (int ct = 0; ct < 3; ++ct) pacc[t][ct] = (f32x4){0.f, 0.f, 0.f, 0.f};

  const bf16x8* w1f = (const bf16x8*)W1F;
  const bf16x8* w2f = (const bf16x8*)W2F;
  unsigned short* hs = Hs;

  for (int g = 0; g < 16; ++g) {               // 32 H-cols per group
    #pragma unroll
    for (int nt = 0; nt < 2; ++nt) {
      int c = g * 2 + nt;                      // 16-col chunk
      bf16x8 bp0 = w1f[(c * 4 + 0) * 64 + lane];   // coalesced
      bf16x8 bp1 = w1f[(c * 4 + 1) * 64 + lane];
      bf16x8 bp2 = w1f[(c * 4 + 2) * 64 + lane];
      bf16x8 bp3 = w1f[(c * 4 + 3) * 64 + lane];
      f32x4 h[4];
      #pragma unroll
      for (int t = 0; t < 4; ++t) h[t] = (f32x4){0.f, 0.f, 0.f, 0.f};
      #pragma unroll
      for (int t = 0; t < 4; ++t) h[t] = __builtin_amdgcn_mfma_f32_16x16x32_bf16(afrag[t][0], bp0, h[t], 0, 0, 0);
      #pragma unroll
      for (int t = 0; t < 4; ++t) h[t] = __builtin_amdgcn_mfma_f32_16x16x32_bf16(afrag[t][1], bp1, h[t], 0, 0, 0);
      #pragma unroll
      for (int t = 0; t < 4; ++t) h[t] = __builtin_amdgcn_mfma_f32_16x16x32_bf16(afrag[t][2], bp2, h[t], 0, 0, 0);
      #pragma unroll
      for (int t = 0; t < 4; ++t) h[t] = __builtin_amdgcn_mfma_f32_16x16x32_bf16(afrag[t][3], bp3, h[t], 0, 0, 0);
      float bias = b1[c * 16 + c16];
      int colb = nt * 16 + (c16 & ~1);
      int rb0  = quad * 4 + (odd ? 2 : 0);
      #pragma unroll
      for (int t = 0; t < 4; ++t) {
        // C layout: lane (c16, quad) reg r -> (row = quad*4+r, col = c16)
        float v0 = fmaxf(h[t][0] + bias, 0.f);
        float v1 = fmaxf(h[t][1] + bias, 0.f);
        float v2 = fmaxf(h[t][2] + bias, 0.f);
        float v3 = fmaxf(h[t][3] + bias, 0.f);
        float o0 = __shfl_xor(v0, 1, 64);
        float o1 = __shfl_xor(v1, 1, 64);
        float o2 = __shfl_xor(v2, 1, 64);
        float o3 = __shfl_xor(v3, 1, 64);
        // even lane stores rows quad*4+{0,1}; odd lane rows quad*4+{2,3}; each b32 = (even col, odd col)
        float lo0 = odd ? o2 : v0, hi0 = odd ? v2 : o0;
        float lo1 = odd ? o3 : v1, hi1 = odd ? v3 : o1;
        unsigned p0, p1;
        asm("v_cvt_pk_bf16_f32 %0, %1, %2" : "=v"(p0) : "v"(lo0), "v"(hi0));   // RNE, == f2bf pair
        asm("v_cvt_pk_bf16_f32 %0, %1, %2" : "=v"(p1) : "v"(lo1), "v"(hi1));
        *(unsigned*)(hs + (t * 16 + rb0    ) * HS_STRIDE + colb) = p0;
        *(unsigned*)(hs + (t * 16 + rb0 + 1) * HS_STRIDE + colb) = p1;
      }
    }
    bf16x8 hf[4];
    #pragma unroll
    for (int t = 0; t < 4; ++t)
      hf[t] = *(const bf16x8*)(hs + (t * 16 + c16) * HS_STRIDE + quad * 8);
    #pragma unroll
    for (int ct = 0; ct < 3; ++ct) {
      bf16x8 bf = w2f[(g * 3 + ct) * 64 + lane];   // coalesced
      #pragma unroll
      for (int t = 0; t < 4; ++t)
        pacc[t][ct] = __builtin_amdgcn_mfma_f32_16x16x32_bf16(hf[t], bf, pacc[t][ct], 0, 0, 0);
    }
  }

  #pragma unroll
  for (int t = 0; t < 4; ++t) {
    int mrow0 = mbase + t * 16 + quad * 4;
    #pragma unroll
    for (int ct = 0; ct < 3; ++ct) {
      int col = ct * 16 + c16;
      if (col < N_CLS) {
        #pragma unroll
        for (int r = 0; r < 4; ++r) {
          int m = mrow0 + r;
          if (m < N_NODES) Pb[(size_t)m * N_CLS + col] = f2bf(pacc[t][ct][r]);
        }
      }
    }
  }
}

// ---------------- layer-2 aggregation (gather bf16, 40-dim) + bias + log_softmax ----------------
// ONE node per 16-lane quarter; 10 active lanes x uint2 (4 packed classes) = 80B row.
// 4 nodes/wave, 4-way unroll => 16 concurrent Pb-row chains per wave. float4 output.
__global__ __launch_bounds__(256) void k_gather2_lsm(const uint2* __restrict__ Pu2,
                                                     const int2* __restrict__ ep,
                                                     const int* __restrict__ offsets,
                                                     const float* __restrict__ dinv, const float* __restrict__ b2,
                                                     float* __restrict__ out) {
  int lane = threadIdx.x & 63, q = lane >> 4, l = lane & 15;
  int d = blockIdx.x * 16 + (threadIdx.x >> 6) * 4 + q;   // 6250 blocks x 16 = 100000 exact
  bool act = l < 10;
  int lc = act ? l : 0;
  int start = offsets[d], end = offsets[d + 1];
  float dd = dinv[d], sl = dd * dd;

  uint2 su = Pu2[(size_t)d * 10 + lc];
  float a0 = sl * blo(su.x), a1 = sl * bhi(su.x), a2 = sl * blo(su.y), a3 = sl * bhi(su.y);
  float p0a = 0.f, p1a = 0.f, p2a = 0.f, p3a = 0.f;
  float q0a = 0.f, q1a = 0.f, q2a = 0.f, q3a = 0.f;
  float r0a = 0.f, r1a = 0.f, r2a = 0.f, r3a = 0.f;

  int i = start;
  for (; i + 3 < end; i += 4) {
    int2 e0 = ep[i], e1 = ep[i + 1], e2 = ep[i + 2], e3 = ep[i + 3];
    uint2 u0 = Pu2[(size_t)e0.x * 10 + lc];
    uint2 u1 = Pu2[(size_t)e1.x * 10 + lc];
    uint2 u2 = Pu2[(size_t)e2.x * 10 + lc];
    uint2 u3 = Pu2[(size_t)e3.x * 10 + lc];
    float n0 = __int_as_float(e0.y), n1 = __int_as_float(e1.y);
    float n2 = __int_as_float(e2.y), n3 = __int_as_float(e3.y);
    a0  += n0 * blo(u0.x); a1  += n0 * bhi(u0.x); a2  += n0 * blo(u0.y); a3  += n0 * bhi(u0.y);
    p0a += n1 * blo(u1.x); p1a += n1 * bhi(u1.x); p2a += n1 * blo(u1.y); p3a += n1 * bhi(u1.y);
    q0a += n2 * blo(u2.x); q1a += n2 * bhi(u2.x); q2a += n2 * blo(u2.y); q3a += n2 * bhi(u2.y);
    r0a += n3 * blo(u3.x); r1a += n3 * bhi(u3.x); r2a += n3 * blo(u3.y); r3a += n3 * bhi(u3.y);
  }
  for (; i < end; ++i) {
    int2 e0 = ep[i];
    uint2 u0 = Pu2[(size_t)e0.x * 10 + lc];
    float n0 = __int_as_float(e0.y);
    a0 += n0 * blo(u0.x); a1 += n0 * bhi(u0.x); a2 += n0 * blo(u0.y); a3 += n0 * bhi(u0.y);
  }

  float v0, v1, v2, v3;
  if (act) {
    float4 bb = ((const float4*)b2)[l];
    v0 = a0 + p0a + q0a + r0a + bb.x;
    v1 = a1 + p1a + q1a + r1a + bb.y;
    v2 = a2 + p2a + q2a + r2a + bb.z;
    v3 = a3 + p3a + q3a + r3a + bb.w;
  } else {
    v0 = v1 = v2 = v3 = -1e30f;
  }
  // log-softmax over 40 classes held by 10 lanes of this quarter (shuffles stay in-quarter)
  float m = fmaxf(fmaxf(v0, v1), fmaxf(v2, v3));
  #pragma unroll
  for (int off = 8; off > 0; off >>= 1) m = fmaxf(m, __shfl_xor(m, off, 64));
  float e = act ? (expf(v0 - m) + expf(v1 - m) + expf(v2 - m) + expf(v3 - m)) : 0.f;
  float s = e;
  #pragma unroll
  for (int off = 8; off > 0; off >>= 1) s += __shfl_xor(s, off, 64);
  float lse = m + logf(s);
  if (act) {
    float4 o = make_float4(v0 - lse, v1 - lse, v2 - lse, v3 - lse);
    ((float4*)(out + (size_t)d * N_CLS))[l] = o;
  }
}

// ---------------- launcher ----------------
extern "C" void kernel_launch(void* const* d_in, const int* in_sizes, int n_in,
                              void* d_out, int out_size, void* d_ws, size_t ws_size,
                              hipStream_t stream) {
  const float* x  = (const float*)d_in[0];
  const int*   ei = (const int*)d_in[1];
  const int*  src = ei;                       // edge_index[0]
  const int*  dst = ei + N_EDGES;             // edge_index[1]
  const float* W1 = (const float*)d_in[2];
  const float* b1 = (const float*)d_in[3];
  const float* W2 = (const float*)d_in[4];
  const float* b2 = (const float*)d_in[5];
  float* out = (float*)d_out;

  // workspace layout (all 16B-aligned). Pb aliases xb2 (dead after k_gather1).
  float* dinv    = (float*)d_ws;                            // 131072 f
  int*   cnt     = (int*)(dinv + 131072);                   // 131072 i
  int*   offsets = cnt + 131072;                            // 131072 i (incl sentinel)
  int*   cursor  = offsets + 131072;                        // 131072 i
  unsigned* flags = (unsigned*)(cursor + 131072);           // 1024 u
  int2*  epair   = (int2*)(flags + 1024);                   // 500000 int2 (pad to 524288)
  uint2* xb2     = (uint2*)(epair + 524288);                // 3.2M uint2 (25.6 MB)
  unsigned short* Pb = (unsigned short*)xb2;                // alias: 4M us (8 MB) — xb dead by then
  unsigned short* z1b = (unsigned short*)(xb2 + 3200000);   // 12.8M us (25.6 MB)
  unsigned short* W1F = z1b + (size_t)N_NODES * IN_DIM;     // 65536 us
  unsigned short* W2F = W1F + HID * IN_DIM;                 // 24576 us

  k_zero <<<(N_NODES + 255) / 256, 256, 0, stream>>>(cnt, flags);
  k_build<<<N_BUILD, 256, 0, stream>>>(src, dst, cnt, flags, offsets, cursor, dinv,
                                       x, xb2, W1, W2, W1F, W2F, epair);
  k_gather1<<<N_NODES / 8, 256, 0, stream>>>(xb2, epair, offsets, dinv, (uint2*)z1b);
  k_fused_mfma<<<(N_NODES + 63) / 64, 64, 0, stream>>>(z1b, W1F, b1, W2F, Pb);
  k_gather2_lsm<<<N_NODES / 16, 256, 0, stream>>>((const uint2*)Pb, epair, offsets, dinv, b2, out);
}

// Round 2
// 249.966 us; speedup vs baseline: 2.0926x; 2.0926x over previous
//
#include <hip/hip_runtime.h>
#include <cstdint>
#include <cstddef>

#define N_NODES 100000
#define N_EDGES 500000
#define IN_DIM  128
#define HID     512
#define N_CLS   40
#define N_SBLK  ((N_NODES + 255) / 256)   // 391 scan blocks
#define N_CNTB  ((N_EDGES + 255) / 256)   // 1954 count blocks
#define N_XBFB  12500                     // xbf blocks (3.2M float4)
#define N_PREPB 352                       // prep blocks

typedef short bf16x8 __attribute__((ext_vector_type(8)));
typedef float f32x4 __attribute__((ext_vector_type(4)));

__device__ inline unsigned short f2bf(float f) {
  unsigned u = __float_as_uint(f);
  u = u + 0x7fffu + ((u >> 16) & 1u);          // RNE
  return (unsigned short)(u >> 16);
}
__device__ inline float blo(unsigned u) { return __uint_as_float(u << 16); }
__device__ inline float bhi(unsigned u) { return __uint_as_float(u & 0xffff0000u); }

// ---------------- CSR build ----------------
__global__ __launch_bounds__(256) void k_zero(int* __restrict__ cnt, unsigned* __restrict__ flags) {
  int i = blockIdx.x * 256 + threadIdx.x;
  if (i < N_NODES) cnt[i] = 0;
  if (i < 512) flags[i] = 0;                   // lookback flags for k_scan_prep
}

// fused: blocks [0,N_CNTB) count in-degrees; blocks [N_CNTB,..) convert x->bf16
__global__ __launch_bounds__(256) void k_count_xbf(const int* __restrict__ dst, int* __restrict__ cnt,
                                                   const float* __restrict__ x, uint2* __restrict__ xb2) {
  int b = blockIdx.x;
  if (b < N_CNTB) {
    int e = b * 256 + threadIdx.x;
    if (e < N_EDGES) atomicAdd(&cnt[dst[e]], 1);
  } else {
    int t = (b - N_CNTB) * 256 + threadIdx.x;  // 3.2M exact
    float4 v = ((const float4*)x)[t];
    uint2 o;
    o.x = (unsigned)f2bf(v.x) | ((unsigned)f2bf(v.y) << 16);
    o.y = (unsigned)f2bf(v.z) | ((unsigned)f2bf(v.w) << 16);
    xb2[t] = o;
  }
}

// single-pass scan (decoupled lookback) fused with weight prep.
// blocks [0,N_SBLK): scan cnt -> offsets/cursor/dinv (+sentinel). blocks beyond: W1F/W2F prep.
// flags[b]: state<<30 | value (value < 2^30). All 743 blocks are co-resident (4 waves, tiny LDS),
// so the spin cannot deadlock; atomics are device-scope (coherent across XCDs).
__global__ __launch_bounds__(256) void k_scan_prep(const int* __restrict__ cnt, unsigned* __restrict__ flags,
                                                   int* __restrict__ offsets, int* __restrict__ cursor,
                                                   float* __restrict__ dinv,
                                                   const float* __restrict__ W1, const float* __restrict__ W2,
                                                   unsigned short* __restrict__ W1F, unsigned short* __restrict__ W2F) {
  int b = blockIdx.x;
  if (b < N_SBLK) {
    __shared__ int s[256];
    __shared__ int base_sh;
    int i = b * 256 + threadIdx.x;
    int v = (i < N_NODES) ? cnt[i] : 0;
    s[threadIdx.x] = v;
    __syncthreads();
    #pragma unroll
    for (int off = 1; off < 256; off <<= 1) {
      int t = (threadIdx.x >= off) ? s[threadIdx.x - off] : 0;
      __syncthreads();
      s[threadIdx.x] += t;
      __syncthreads();
    }
    int incl = s[threadIdx.x];
    if (threadIdx.x == 0) {
      int total = s[255];
      if (b == 0) {
        atomicExch(&flags[0], (2u << 30) | (unsigned)total);
        base_sh = 0;
      } else {
        atomicExch(&flags[b], (1u << 30) | (unsigned)total);
        int base = 0, pred = b - 1;
        while (true) {
          unsigned f;
          do { f = atomicAdd(&flags[pred], 0u); } while ((f >> 30) == 0u);
          base += (int)(f & 0x3fffffffu);
          if ((f >> 30) == 2u) break;
          --pred;
        }
        atomicExch(&flags[b], (2u << 30) | (unsigned)(base + (unsigned)total));
        base_sh = base;
      }
    }
    __syncthreads();
    int gbase = base_sh;
    if (i < N_NODES) {
      int excl = gbase + incl - v;
      offsets[i] = excl;
      cursor[i]  = excl;
      dinv[i]    = rsqrtf((float)(v + 1));     // +1 self-loop
    }
    if (b == 0 && threadIdx.x == 0) offsets[N_NODES] = N_EDGES;   // sentinel
  } else {
    int t = (b - N_SBLK) * 256 + threadIdx.x;  // 90112 exact
    if (t < 65536) {
      int j = t & 7, lane = (t >> 3) & 63, rest = t >> 9;   // rest = c*4+s
      int s2 = rest & 3, c = rest >> 2;
      int k = s2 * 32 + (lane >> 4) * 8 + j;
      int n = c * 16 + (lane & 15);
      W1F[t] = f2bf(W1[k * HID + n]);
    } else {
      int u = t - 65536;                        // 24576
      int j = u & 7, lane = (u >> 3) & 63, rest = u >> 9;   // rest = gk*3+ct
      int ct = rest % 3, gk = rest / 3;
      int k = gk * 32 + (lane >> 4) * 8 + j;
      int col = ct * 16 + (lane & 15);
      W2F[u] = (col < N_CLS) ? f2bf(W2[k * N_CLS + col]) : (unsigned short)0;
    }
  }
}

// fill CSR with (src, norm) pairs
__global__ __launch_bounds__(256) void k_fill(const int* __restrict__ src, const int* __restrict__ dst,
                                              const float* __restrict__ dinv,
                                              int* __restrict__ cursor, int2* __restrict__ epair) {
  int e = blockIdx.x * 256 + threadIdx.x;
  if (e >= N_EDGES) return;
  int s = src[e], d = dst[e];
  int pos = atomicAdd(&cursor[d], 1);
  float nrm = dinv[s] * dinv[d];
  epair[pos] = make_int2(s, __float_as_int(nrm));
}

// ---------------- layer-1 aggregation (gather, bf16): Z1 = Ahat @ X ----------------
// ONE node per 32-lane half (row = 32 x uint2 = 256B); 2 nodes/wave; 4-way unroll
// => 8 concurrent row chains per wave, no cross-lane reduction needed.
__global__ __launch_bounds__(256) void k_gather1(const uint2* __restrict__ xb, const int2* __restrict__ ep,
                                                 const int* __restrict__ offsets,
                                                 const float* __restrict__ dinv, uint2* __restrict__ z1) {
  int lane = threadIdx.x & 63, h = lane >> 5, l = lane & 31;
  int d = blockIdx.x * 8 + (threadIdx.x >> 6) * 2 + h;   // 12500 blocks x 8 = 100000 exact
  int start = offsets[d], end = offsets[d + 1];
  float dd = dinv[d], sl = dd * dd;
  uint2 su = xb[(size_t)d * 32 + l];
  float a0 = sl * blo(su.x), a1 = sl * bhi(su.x), a2 = sl * blo(su.y), a3 = sl * bhi(su.y);
  float p0a = 0.f, p1a = 0.f, p2a = 0.f, p3a = 0.f;
  float q0a = 0.f, q1a = 0.f, q2a = 0.f, q3a = 0.f;
  float r0a = 0.f, r1a = 0.f, r2a = 0.f, r3a = 0.f;

  int i = start;
  for (; i + 3 < end; i += 4) {
    int2 e0 = ep[i], e1 = ep[i + 1], e2 = ep[i + 2], e3 = ep[i + 3];
    uint2 r0 = xb[(size_t)e0.x * 32 + l];
    uint2 r1 = xb[(size_t)e1.x * 32 + l];
    uint2 r2 = xb[(size_t)e2.x * 32 + l];
    uint2 r3 = xb[(size_t)e3.x * 32 + l];
    float n0 = __int_as_float(e0.y), n1 = __int_as_float(e1.y);
    float n2 = __int_as_float(e2.y), n3 = __int_as_float(e3.y);
    a0  += n0 * blo(r0.x); a1  += n0 * bhi(r0.x); a2  += n0 * blo(r0.y); a3  += n0 * bhi(r0.y);
    p0a += n1 * blo(r1.x); p1a += n1 * bhi(r1.x); p2a += n1 * blo(r1.y); p3a += n1 * bhi(r1.y);
    q0a += n2 * blo(r2.x); q1a += n2 * bhi(r2.x); q2a += n2 * blo(r2.y); q3a += n2 * bhi(r2.y);
    r0a += n3 * blo(r3.x); r1a += n3 * bhi(r3.x); r2a += n3 * blo(r3.y); r3a += n3 * bhi(r3.y);
  }
  for (; i < end; ++i) {
    int2 e0 = ep[i];
    uint2 r0 = xb[(size_t)e0.x * 32 + l];
    float n0 = __int_as_float(e0.y);
    a0 += n0 * blo(r0.x); a1 += n0 * bhi(r0.x); a2 += n0 * blo(r0.y); a3 += n0 * bhi(r0.y);
  }
  a0 += p0a + q0a + r0a;
  a1 += p1a + q1a + r1a;
  a2 += p2a + q2a + r2a;
  a3 += p3a + q3a + r3a;
  uint2 o;
  o.x = (unsigned)f2bf(a0) | ((unsigned)f2bf(a1) << 16);
  o.y = (unsigned)f2bf(a2) | ((unsigned)f2bf(a3) << 16);
  z1[(size_t)d * 32 + l] = o;
}

// ---------------- fused GEMM1+bias+relu+GEMM2 via bf16 MFMA ----------------
// 1 wave per block, 64 rows (4 m-tiles): every B-fragment load feeds 16 MFMAs.
// 1563 blocks -> better tail than 391x4-wave blocks. No __syncthreads needed.
// Epilogue: pair-swap (shfl_xor 1) + v_cvt_pk_bf16_f32 -> b32 LDS stores
// (2 per t,nt instead of 4 u16 stores + 16 f2bf ops). Readback stays b128.
#define HS_STRIDE 56   // ushorts; 112B rows: 16B-aligned b128 reads, worst 2-way conflict = free
__global__ __launch_bounds__(64) void k_fused_mfma(const unsigned short* __restrict__ z1b,
                                                   const unsigned short* __restrict__ W1F,
                                                   const float* __restrict__ b1,
                                                   const unsigned short* __restrict__ W2F,
                                                   unsigned short* __restrict__ Pb) {
  __shared__ unsigned short Hs[64 * HS_STRIDE];   // 7168 B
  const int lane = threadIdx.x;                   // 0..63 (one wave)
  const int c16  = lane & 15, quad = lane >> 4;
  const int odd  = c16 & 1;
  const int mbase = blockIdx.x * 64;              // 1563 blocks x 64 >= 100000

  bf16x8 afrag[4][4];
  #pragma unroll
  for (int t = 0; t < 4; ++t) {
    int mrow = mbase + t * 16 + c16;
    int meff = (mrow < N_NODES) ? mrow : 0;
    const bf16x8* arow = (const bf16x8*)(z1b + (size_t)meff * IN_DIM + quad * 8);
    afrag[t][0] = arow[0];
    afrag[t][1] = arow[4];     // +32 ushorts
    afrag[t][2] = arow[8];
    afrag[t][3] = arow[12];
  }

  f32x4 pacc[4][3];
  #pragma unroll
  for (int t = 0; t < 4; ++t)
    #pragma unroll
    for (int ct = 0; ct < 3; ++ct) pacc[t][ct] = (f32x4){0.f, 0.f, 0.f, 0.f};

  const bf16x8* w1f = (const bf16x8*)W1F;
  const bf16x8* w2f = (const bf16x8*)W2F;
  unsigned short* hs = Hs;

  for (int g = 0; g < 16; ++g) {               // 32 H-cols per group
    #pragma unroll
    for (int nt = 0; nt < 2; ++nt) {
      int c = g * 2 + nt;                      // 16-col chunk
      bf16x8 bp0 = w1f[(c * 4 + 0) * 64 + lane];   // coalesced
      bf16x8 bp1 = w1f[(c * 4 + 1) * 64 + lane];
      bf16x8 bp2 = w1f[(c * 4 + 2) * 64 + lane];
      bf16x8 bp3 = w1f[(c * 4 + 3) * 64 + lane];
      f32x4 h[4];
      #pragma unroll
      for (int t = 0; t < 4; ++t) h[t] = (f32x4){0.f, 0.f, 0.f, 0.f};
      #pragma unroll
      for (int t = 0; t < 4; ++t) h[t] = __builtin_amdgcn_mfma_f32_16x16x32_bf16(afrag[t][0], bp0, h[t], 0, 0, 0);
      #pragma unroll
      for (int t = 0; t < 4; ++t) h[t] = __builtin_amdgcn_mfma_f32_16x16x32_bf16(afrag[t][1], bp1, h[t], 0, 0, 0);
      #pragma unroll
      for (int t = 0; t < 4; ++t) h[t] = __builtin_amdgcn_mfma_f32_16x16x32_bf16(afrag[t][2], bp2, h[t], 0, 0, 0);
      #pragma unroll
      for (int t = 0; t < 4; ++t) h[t] = __builtin_amdgcn_mfma_f32_16x16x32_bf16(afrag[t][3], bp3, h[t], 0, 0, 0);
      float bias = b1[c * 16 + c16];
      int colb = nt * 16 + (c16 & ~1);
      int rb0  = quad * 4 + (odd ? 2 : 0);
      #pragma unroll
      for (int t = 0; t < 4; ++t) {
        // C layout: lane (c16, quad) reg r -> (row = quad*4+r, col = c16)
        float v0 = fmaxf(h[t][0] + bias, 0.f);
        float v1 = fmaxf(h[t][1] + bias, 0.f);
        float v2 = fmaxf(h[t][2] + bias, 0.f);
        float v3 = fmaxf(h[t][3] + bias, 0.f);
        float o0 = __shfl_xor(v0, 1, 64);
        float o1 = __shfl_xor(v1, 1, 64);
        float o2 = __shfl_xor(v2, 1, 64);
        float o3 = __shfl_xor(v3, 1, 64);
        // even lane stores rows quad*4+{0,1}; odd lane rows quad*4+{2,3}; each b32 = (even col, odd col)
        float lo0 = odd ? o2 : v0, hi0 = odd ? v2 : o0;
        float lo1 = odd ? o3 : v1, hi1 = odd ? v3 : o1;
        unsigned p0, p1;
        asm("v_cvt_pk_bf16_f32 %0, %1, %2" : "=v"(p0) : "v"(lo0), "v"(hi0));   // RNE, == f2bf pair
        asm("v_cvt_pk_bf16_f32 %0, %1, %2" : "=v"(p1) : "v"(lo1), "v"(hi1));
        *(unsigned*)(hs + (t * 16 + rb0    ) * HS_STRIDE + colb) = p0;
        *(unsigned*)(hs + (t * 16 + rb0 + 1) * HS_STRIDE + colb) = p1;
      }
    }
    bf16x8 hf[4];
    #pragma unroll
    for (int t = 0; t < 4; ++t)
      hf[t] = *(const bf16x8*)(hs + (t * 16 + c16) * HS_STRIDE + quad * 8);
    #pragma unroll
    for (int ct = 0; ct < 3; ++ct) {
      bf16x8 bf = w2f[(g * 3 + ct) * 64 + lane];   // coalesced
      #pragma unroll
      for (int t = 0; t < 4; ++t)
        pacc[t][ct] = __builtin_amdgcn_mfma_f32_16x16x32_bf16(hf[t], bf, pacc[t][ct], 0, 0, 0);
    }
  }

  #pragma unroll
  for (int t = 0; t < 4; ++t) {
    int mrow0 = mbase + t * 16 + quad * 4;
    #pragma unroll
    for (int ct = 0; ct < 3; ++ct) {
      int col = ct * 16 + c16;
      if (col < N_CLS) {
        #pragma unroll
        for (int r = 0; r < 4; ++r) {
          int m = mrow0 + r;
          if (m < N_NODES) Pb[(size_t)m * N_CLS + col] = f2bf(pacc[t][ct][r]);
        }
      }
    }
  }
}

// ---------------- layer-2 aggregation (gather bf16, 40-dim) + bias + log_softmax ----------------
// ONE node per 16-lane quarter; 10 active lanes x uint2 (4 packed classes) = 80B row.
// 4 nodes/wave, 4-way unroll => 16 concurrent Pb-row chains per wave. float4 output.
__global__ __launch_bounds__(256) void k_gather2_lsm(const uint2* __restrict__ Pu2,
                                                     const int2* __restrict__ ep,
                                                     const int* __restrict__ offsets,
                                                     const float* __restrict__ dinv, const float* __restrict__ b2,
                                                     float* __restrict__ out) {
  int lane = threadIdx.x & 63, q = lane >> 4, l = lane & 15;
  int d = blockIdx.x * 16 + (threadIdx.x >> 6) * 4 + q;   // 6250 blocks x 16 = 100000 exact
  bool act = l < 10;
  int lc = act ? l : 0;
  int start = offsets[d], end = offsets[d + 1];
  float dd = dinv[d], sl = dd * dd;

  uint2 su = Pu2[(size_t)d * 10 + lc];
  float a0 = sl * blo(su.x), a1 = sl * bhi(su.x), a2 = sl * blo(su.y), a3 = sl * bhi(su.y);
  float p0a = 0.f, p1a = 0.f, p2a = 0.f, p3a = 0.f;
  float q0a = 0.f, q1a = 0.f, q2a = 0.f, q3a = 0.f;
  float r0a = 0.f, r1a = 0.f, r2a = 0.f, r3a = 0.f;

  int i = start;
  for (; i + 3 < end; i += 4) {
    int2 e0 = ep[i], e1 = ep[i + 1], e2 = ep[i + 2], e3 = ep[i + 3];
    uint2 u0 = Pu2[(size_t)e0.x * 10 + lc];
    uint2 u1 = Pu2[(size_t)e1.x * 10 + lc];
    uint2 u2 = Pu2[(size_t)e2.x * 10 + lc];
    uint2 u3 = Pu2[(size_t)e3.x * 10 + lc];
    float n0 = __int_as_float(e0.y), n1 = __int_as_float(e1.y);
    float n2 = __int_as_float(e2.y), n3 = __int_as_float(e3.y);
    a0  += n0 * blo(u0.x); a1  += n0 * bhi(u0.x); a2  += n0 * blo(u0.y); a3  += n0 * bhi(u0.y);
    p0a += n1 * blo(u1.x); p1a += n1 * bhi(u1.x); p2a += n1 * blo(u1.y); p3a += n1 * bhi(u1.y);
    q0a += n2 * blo(u2.x); q1a += n2 * bhi(u2.x); q2a += n2 * blo(u2.y); q3a += n2 * bhi(u2.y);
    r0a += n3 * blo(u3.x); r1a += n3 * bhi(u3.x); r2a += n3 * blo(u3.y); r3a += n3 * bhi(u3.y);
  }
  for (; i < end; ++i) {
    int2 e0 = ep[i];
    uint2 u0 = Pu2[(size_t)e0.x * 10 + lc];
    float n0 = __int_as_float(e0.y);
    a0 += n0 * blo(u0.x); a1 += n0 * bhi(u0.x); a2 += n0 * blo(u0.y); a3 += n0 * bhi(u0.y);
  }

  float v0, v1, v2, v3;
  if (act) {
    float4 bb = ((const float4*)b2)[l];
    v0 = a0 + p0a + q0a + r0a + bb.x;
    v1 = a1 + p1a + q1a + r1a + bb.y;
    v2 = a2 + p2a + q2a + r2a + bb.z;
    v3 = a3 + p3a + q3a + r3a + bb.w;
  } else {
    v0 = v1 = v2 = v3 = -1e30f;
  }
  // log-softmax over 40 classes held by 10 lanes of this quarter (shuffles stay in-quarter)
  float m = fmaxf(fmaxf(v0, v1), fmaxf(v2, v3));
  #pragma unroll
  for (int off = 8; off > 0; off >>= 1) m = fmaxf(m, __shfl_xor(m, off, 64));
  float e = act ? (expf(v0 - m) + expf(v1 - m) + expf(v2 - m) + expf(v3 - m)) : 0.f;
  float s = e;
  #pragma unroll
  for (int off = 8; off > 0; off >>= 1) s += __shfl_xor(s, off, 64);
  float lse = m + logf(s);
  if (act) {
    float4 o = make_float4(v0 - lse, v1 - lse, v2 - lse, v3 - lse);
    ((float4*)(out + (size_t)d * N_CLS))[l] = o;
  }
}

// ---------------- launcher ----------------
extern "C" void kernel_launch(void* const* d_in, const int* in_sizes, int n_in,
                              void* d_out, int out_size, void* d_ws, size_t ws_size,
                              hipStream_t stream) {
  const float* x  = (const float*)d_in[0];
  const int*   ei = (const int*)d_in[1];
  const int*  src = ei;                       // edge_index[0]
  const int*  dst = ei + N_EDGES;             // edge_index[1]
  const float* W1 = (const float*)d_in[2];
  const float* b1 = (const float*)d_in[3];
  const float* W2 = (const float*)d_in[4];
  const float* b2 = (const float*)d_in[5];
  float* out = (float*)d_out;

  // workspace layout (all 16B-aligned). Pb aliases xb2 (dead after k_gather1).
  float* dinv    = (float*)d_ws;                            // 131072 f
  int*   cnt     = (int*)(dinv + 131072);                   // 131072 i
  int*   offsets = cnt + 131072;                            // 131072 i (incl sentinel)
  int*   cursor  = offsets + 131072;                        // 131072 i
  unsigned* flags = (unsigned*)(cursor + 131072);           // 1024 u
  int2*  epair   = (int2*)(flags + 1024);                   // 500000 int2 (pad to 524288)
  uint2* xb2     = (uint2*)(epair + 524288);                // 3.2M uint2 (25.6 MB)
  unsigned short* Pb = (unsigned short*)xb2;                // alias: 4M us (8 MB) — xb dead by then
  unsigned short* z1b = (unsigned short*)(xb2 + 3200000);   // 12.8M us (25.6 MB)
  unsigned short* W1F = z1b + (size_t)N_NODES * IN_DIM;     // 65536 us
  unsigned short* W2F = W1F + HID * IN_DIM;                 // 24576 us

  k_zero <<<(N_NODES + 255) / 256, 256, 0, stream>>>(cnt, flags);
  k_count_xbf<<<N_CNTB + N_XBFB, 256, 0, stream>>>(dst, cnt, x, xb2);
  k_scan_prep<<<N_SBLK + N_PREPB, 256, 0, stream>>>(cnt, flags, offsets, cursor, dinv, W1, W2, W1F, W2F);
  k_fill <<<N_CNTB, 256, 0, stream>>>(src, dst, dinv, cursor, epair);
  k_gather1<<<N_NODES / 8, 256, 0, stream>>>(xb2, epair, offsets, dinv, (uint2*)z1b);
  k_fused_mfma<<<(N_NODES + 63) / 64, 64, 0, stream>>>(z1b, W1F, b1, W2F, Pb);
  k_gather2_lsm<<<N_NODES / 16, 256, 0, stream>>>((const uint2*)Pb, epair, offsets, dinv, b2, out);
}

// Round 3
// 238.822 us; speedup vs baseline: 2.1902x; 1.0467x over previous
//
#include <hip/hip_runtime.h>
#include <cstdint>
#include <cstddef>

#define N_NODES 100000
#define N_EDGES 500000
#define IN_DIM  128
#define HID     512
#define N_CLS   40
#define N_SBLK  ((N_NODES + 255) / 256)   // 391 scan blocks
#define N_CNTB  ((N_EDGES + 255) / 256)   // 1954 count blocks
#define N_XBFB  12500                     // xbf blocks (3.2M float4)
#define N_PREPB 352                       // prep blocks

typedef short bf16x8 __attribute__((ext_vector_type(8)));
typedef float f32x4 __attribute__((ext_vector_type(4)));

__device__ inline unsigned short f2bf(float f) {
  unsigned u = __float_as_uint(f);
  u = u + 0x7fffu + ((u >> 16) & 1u);          // RNE
  return (unsigned short)(u >> 16);
}
__device__ inline float blo(unsigned u) { return __uint_as_float(u << 16); }
__device__ inline float bhi(unsigned u) { return __uint_as_float(u & 0xffff0000u); }

// ---------------- CSR build ----------------
__global__ __launch_bounds__(256) void k_zero(int* __restrict__ cnt, unsigned* __restrict__ flags) {
  int i = blockIdx.x * 256 + threadIdx.x;
  if (i < N_NODES) cnt[i] = 0;
  if (i < 512) flags[i] = 0;                   // flags[0] = global segment allocator
}

// fused: blocks [0,N_CNTB) count in-degrees; blocks [N_CNTB,..) convert x->bf16
__global__ __launch_bounds__(256) void k_count_xbf(const int* __restrict__ dst, int* __restrict__ cnt,
                                                   const float* __restrict__ x, uint2* __restrict__ xb2) {
  int b = blockIdx.x;
  if (b < N_CNTB) {
    int e = b * 256 + threadIdx.x;
    if (e < N_EDGES) atomicAdd(&cnt[dst[e]], 1);
  } else {
    int t = (b - N_CNTB) * 256 + threadIdx.x;  // 3.2M exact
    float4 v = ((const float4*)x)[t];
    uint2 o;
    o.x = (unsigned)f2bf(v.x) | ((unsigned)f2bf(v.y) << 16);
    o.y = (unsigned)f2bf(v.z) | ((unsigned)f2bf(v.w) << 16);
    xb2[t] = o;
  }
}

// Arrival-order scan fused with weight prep. Segment ORDER is irrelevant (aggregation is an
// order-independent sum); each scan block takes a disjoint range of epair positions via ONE
// atomicAdd on a global allocator (flags[0]) — no lookback, no serial publication cascade.
// Consumers compute segment end as offsets[d] + cnt[d] (offsets no longer monotone).
__global__ __launch_bounds__(256) void k_scan_prep(const int* __restrict__ cnt, unsigned* __restrict__ flags,
                                                   int* __restrict__ offsets, int* __restrict__ cursor,
                                                   float* __restrict__ dinv,
                                                   const float* __restrict__ W1, const float* __restrict__ W2,
                                                   unsigned short* __restrict__ W1F, unsigned short* __restrict__ W2F) {
  int b = blockIdx.x;
  if (b < N_SBLK) {
    __shared__ int s[256];
    __shared__ int base_sh;
    int i = b * 256 + threadIdx.x;
    int v = (i < N_NODES) ? cnt[i] : 0;
    s[threadIdx.x] = v;
    __syncthreads();
    #pragma unroll
    for (int off = 1; off < 256; off <<= 1) {
      int t = (threadIdx.x >= off) ? s[threadIdx.x - off] : 0;
      __syncthreads();
      s[threadIdx.x] += t;
      __syncthreads();
    }
    int incl = s[threadIdx.x];
    if (threadIdx.x == 0)
      base_sh = (int)atomicAdd(&flags[0], (unsigned)s[255]);   // arrival-order base
    __syncthreads();
    int gbase = base_sh;
    if (i < N_NODES) {
      int excl = gbase + incl - v;
      offsets[i] = excl;
      cursor[i]  = excl;
      dinv[i]    = rsqrtf((float)(v + 1));     // +1 self-loop
    }
  } else {
    int t = (b - N_SBLK) * 256 + threadIdx.x;  // 90112 exact
    if (t < 65536) {
      int j = t & 7, lane = (t >> 3) & 63, rest = t >> 9;   // rest = c*4+s
      int s2 = rest & 3, c = rest >> 2;
      int k = s2 * 32 + (lane >> 4) * 8 + j;
      int n = c * 16 + (lane & 15);
      W1F[t] = f2bf(W1[k * HID + n]);
    } else {
      int u = t - 65536;                        // 24576
      int j = u & 7, lane = (u >> 3) & 63, rest = u >> 9;   // rest = gk*3+ct
      int ct = rest % 3, gk = rest / 3;
      int k = gk * 32 + (lane >> 4) * 8 + j;
      int col = ct * 16 + (lane & 15);
      W2F[u] = (col < N_CLS) ? f2bf(W2[k * N_CLS + col]) : (unsigned short)0;
    }
  }
}

// fill CSR with (src, norm) pairs
__global__ __launch_bounds__(256) void k_fill(const int* __restrict__ src, const int* __restrict__ dst,
                                              const float* __restrict__ dinv,
                                              int* __restrict__ cursor, int2* __restrict__ epair) {
  int e = blockIdx.x * 256 + threadIdx.x;
  if (e >= N_EDGES) return;
  int s = src[e], d = dst[e];
  int pos = atomicAdd(&cursor[d], 1);
  float nrm = dinv[s] * dinv[d];
  epair[pos] = make_int2(s, __float_as_int(nrm));
}

// ---------------- layer-1 aggregation (gather, bf16): Z1 = Ahat @ X ----------------
// ONE node per 32-lane half (row = 32 x uint2 = 256B); 2 nodes/wave; 4-way unroll
// => 8 concurrent row chains per wave, no cross-lane reduction needed.
// Segment end = offsets[d] + cnt[d] (arrival-order offsets are not monotone).
__global__ __launch_bounds__(256) void k_gather1(const uint2* __restrict__ xb, const int2* __restrict__ ep,
                                                 const int* __restrict__ offsets, const int* __restrict__ cnt,
                                                 const float* __restrict__ dinv, uint2* __restrict__ z1) {
  int lane = threadIdx.x & 63, h = lane >> 5, l = lane & 31;
  int d = blockIdx.x * 8 + (threadIdx.x >> 6) * 2 + h;   // 12500 blocks x 8 = 100000 exact
  int start = offsets[d], end = start + cnt[d];
  float dd = dinv[d], sl = dd * dd;
  uint2 su = xb[(size_t)d * 32 + l];
  float a0 = sl * blo(su.x), a1 = sl * bhi(su.x), a2 = sl * blo(su.y), a3 = sl * bhi(su.y);
  float p0a = 0.f, p1a = 0.f, p2a = 0.f, p3a = 0.f;
  float q0a = 0.f, q1a = 0.f, q2a = 0.f, q3a = 0.f;
  float r0a = 0.f, r1a = 0.f, r2a = 0.f, r3a = 0.f;

  int i = start;
  for (; i + 3 < end; i += 4) {
    int2 e0 = ep[i], e1 = ep[i + 1], e2 = ep[i + 2], e3 = ep[i + 3];
    uint2 r0 = xb[(size_t)e0.x * 32 + l];
    uint2 r1 = xb[(size_t)e1.x * 32 + l];
    uint2 r2 = xb[(size_t)e2.x * 32 + l];
    uint2 r3 = xb[(size_t)e3.x * 32 + l];
    float n0 = __int_as_float(e0.y), n1 = __int_as_float(e1.y);
    float n2 = __int_as_float(e2.y), n3 = __int_as_float(e3.y);
    a0  += n0 * blo(r0.x); a1  += n0 * bhi(r0.x); a2  += n0 * blo(r0.y); a3  += n0 * bhi(r0.y);
    p0a += n1 * blo(r1.x); p1a += n1 * bhi(r1.x); p2a += n1 * blo(r1.y); p3a += n1 * bhi(r1.y);
    q0a += n2 * blo(r2.x); q1a += n2 * bhi(r2.x); q2a += n2 * blo(r2.y); q3a += n2 * bhi(r2.y);
    r0a += n3 * blo(r3.x); r1a += n3 * bhi(r3.x); r2a += n3 * blo(r3.y); r3a += n3 * bhi(r3.y);
  }
  for (; i < end; ++i) {
    int2 e0 = ep[i];
    uint2 r0 = xb[(size_t)e0.x * 32 + l];
    float n0 = __int_as_float(e0.y);
    a0 += n0 * blo(r0.x); a1 += n0 * bhi(r0.x); a2 += n0 * blo(r0.y); a3 += n0 * bhi(r0.y);
  }
  a0 += p0a + q0a + r0a;
  a1 += p1a + q1a + r1a;
  a2 += p2a + q2a + r2a;
  a3 += p3a + q3a + r3a;
  uint2 o;
  o.x = (unsigned)f2bf(a0) | ((unsigned)f2bf(a1) << 16);
  o.y = (unsigned)f2bf(a2) | ((unsigned)f2bf(a3) << 16);
  z1[(size_t)d * 32 + l] = o;
}

// ---------------- fused GEMM1+bias+relu+GEMM2 via bf16 MFMA ----------------
// 1 wave per block, 64 rows (4 m-tiles): every B-fragment load feeds 16 MFMAs.
// Epilogue: pair-swap (shfl_xor 1) + v_cvt_pk_bf16_f32 -> b32 LDS stores.
#define HS_STRIDE 56   // ushorts; 112B rows: 16B-aligned b128 reads, worst 2-way conflict = free
__global__ __launch_bounds__(64) void k_fused_mfma(const unsigned short* __restrict__ z1b,
                                                   const unsigned short* __restrict__ W1F,
                                                   const float* __restrict__ b1,
                                                   const unsigned short* __restrict__ W2F,
                                                   unsigned short* __restrict__ Pb) {
  __shared__ unsigned short Hs[64 * HS_STRIDE];   // 7168 B
  const int lane = threadIdx.x;                   // 0..63 (one wave)
  const int c16  = lane & 15, quad = lane >> 4;
  const int odd  = c16 & 1;
  const int mbase = blockIdx.x * 64;              // 1563 blocks x 64 >= 100000

  bf16x8 afrag[4][4];
  #pragma unroll
  for (int t = 0; t < 4; ++t) {
    int mrow = mbase + t * 16 + c16;
    int meff = (mrow < N_NODES) ? mrow : 0;
    const bf16x8* arow = (const bf16x8*)(z1b + (size_t)meff * IN_DIM + quad * 8);
    afrag[t][0] = arow[0];
    afrag[t][1] = arow[4];     // +32 ushorts
    afrag[t][2] = arow[8];
    afrag[t][3] = arow[12];
  }

  f32x4 pacc[4][3];
  #pragma unroll
  for (int t = 0; t < 4; ++t)
    #pragma unroll
    for (int ct = 0; ct < 3; ++ct) pacc[t][ct] = (f32x4){0.f, 0.f, 0.f, 0.f};

  const bf16x8* w1f = (const bf16x8*)W1F;
  const bf16x8* w2f = (const bf16x8*)W2F;
  unsigned short* hs = Hs;

  for (int g = 0; g < 16; ++g) {               // 32 H-cols per group
    #pragma unroll
    for (int nt = 0; nt < 2; ++nt) {
      int c = g * 2 + nt;                      // 16-col chunk
      bf16x8 bp0 = w1f[(c * 4 + 0) * 64 + lane];   // coalesced
      bf16x8 bp1 = w1f[(c * 4 + 1) * 64 + lane];
      bf16x8 bp2 = w1f[(c * 4 + 2) * 64 + lane];
      bf16x8 bp3 = w1f[(c * 4 + 3) * 64 + lane];
      f32x4 h[4];
      #pragma unroll
      for (int t = 0; t < 4; ++t) h[t] = (f32x4){0.f, 0.f, 0.f, 0.f};
      #pragma unroll
      for (int t = 0; t < 4; ++t) h[t] = __builtin_amdgcn_mfma_f32_16x16x32_bf16(afrag[t][0], bp0, h[t], 0, 0, 0);
      #pragma unroll
      for (int t = 0; t < 4; ++t) h[t] = __builtin_amdgcn_mfma_f32_16x16x32_bf16(afrag[t][1], bp1, h[t], 0, 0, 0);
      #pragma unroll
      for (int t = 0; t < 4; ++t) h[t] = __builtin_amdgcn_mfma_f32_16x16x32_bf16(afrag[t][2], bp2, h[t], 0, 0, 0);
      #pragma unroll
      for (int t = 0; t < 4; ++t) h[t] = __builtin_amdgcn_mfma_f32_16x16x32_bf16(afrag[t][3], bp3, h[t], 0, 0, 0);
      float bias = b1[c * 16 + c16];
      int colb = nt * 16 + (c16 & ~1);
      int rb0  = quad * 4 + (odd ? 2 : 0);
      #pragma unroll
      for (int t = 0; t < 4; ++t) {
        // C layout: lane (c16, quad) reg r -> (row = quad*4+r, col = c16)
        float v0 = fmaxf(h[t][0] + bias, 0.f);
        float v1 = fmaxf(h[t][1] + bias, 0.f);
        float v2 = fmaxf(h[t][2] + bias, 0.f);
        float v3 = fmaxf(h[t][3] + bias, 0.f);
        float o0 = __shfl_xor(v0, 1, 64);
        float o1 = __shfl_xor(v1, 1, 64);
        float o2 = __shfl_xor(v2, 1, 64);
        float o3 = __shfl_xor(v3, 1, 64);
        // even lane stores rows quad*4+{0,1}; odd lane rows quad*4+{2,3}; each b32 = (even col, odd col)
        float lo0 = odd ? o2 : v0, hi0 = odd ? v2 : o0;
        float lo1 = odd ? o3 : v1, hi1 = odd ? v3 : o1;
        unsigned p0, p1;
        asm("v_cvt_pk_bf16_f32 %0, %1, %2" : "=v"(p0) : "v"(lo0), "v"(hi0));   // RNE, == f2bf pair
        asm("v_cvt_pk_bf16_f32 %0, %1, %2" : "=v"(p1) : "v"(lo1), "v"(hi1));
        *(unsigned*)(hs + (t * 16 + rb0    ) * HS_STRIDE + colb) = p0;
        *(unsigned*)(hs + (t * 16 + rb0 + 1) * HS_STRIDE + colb) = p1;
      }
    }
    bf16x8 hf[4];
    #pragma unroll
    for (int t = 0; t < 4; ++t)
      hf[t] = *(const bf16x8*)(hs + (t * 16 + c16) * HS_STRIDE + quad * 8);
    #pragma unroll
    for (int ct = 0; ct < 3; ++ct) {
      bf16x8 bf = w2f[(g * 3 + ct) * 64 + lane];   // coalesced
      #pragma unroll
      for (int t = 0; t < 4; ++t)
        pacc[t][ct] = __builtin_amdgcn_mfma_f32_16x16x32_bf16(hf[t], bf, pacc[t][ct], 0, 0, 0);
    }
  }

  #pragma unroll
  for (int t = 0; t < 4; ++t) {
    int mrow0 = mbase + t * 16 + quad * 4;
    #pragma unroll
    for (int ct = 0; ct < 3; ++ct) {
      int col = ct * 16 + c16;
      if (col < N_CLS) {
        #pragma unroll
        for (int r = 0; r < 4; ++r) {
          int m = mrow0 + r;
          if (m < N_NODES) Pb[(size_t)m * N_CLS + col] = f2bf(pacc[t][ct][r]);
        }
      }
    }
  }
}

// ---------------- layer-2 aggregation (gather bf16, 40-dim) + bias + log_softmax ----------------
// ONE node per 16-lane quarter; 10 active lanes x uint2 (4 packed classes) = 80B row.
// 4 nodes/wave, 4-way unroll => 16 concurrent Pb-row chains per wave. float4 output.
// Segment end = offsets[d] + cnt[d] (arrival-order offsets are not monotone).
__global__ __launch_bounds__(256) void k_gather2_lsm(const uint2* __restrict__ Pu2,
                                                     const int2* __restrict__ ep,
                                                     const int* __restrict__ offsets, const int* __restrict__ cnt,
                                                     const float* __restrict__ dinv, const float* __restrict__ b2,
                                                     float* __restrict__ out) {
  int lane = threadIdx.x & 63, q = lane >> 4, l = lane & 15;
  int d = blockIdx.x * 16 + (threadIdx.x >> 6) * 4 + q;   // 6250 blocks x 16 = 100000 exact
  bool act = l < 10;
  int lc = act ? l : 0;
  int start = offsets[d], end = start + cnt[d];
  float dd = dinv[d], sl = dd * dd;

  uint2 su = Pu2[(size_t)d * 10 + lc];
  float a0 = sl * blo(su.x), a1 = sl * bhi(su.x), a2 = sl * blo(su.y), a3 = sl * bhi(su.y);
  float p0a = 0.f, p1a = 0.f, p2a = 0.f, p3a = 0.f;
  float q0a = 0.f, q1a = 0.f, q2a = 0.f, q3a = 0.f;
  float r0a = 0.f, r1a = 0.f, r2a = 0.f, r3a = 0.f;

  int i = start;
  for (; i + 3 < end; i += 4) {
    int2 e0 = ep[i], e1 = ep[i + 1], e2 = ep[i + 2], e3 = ep[i + 3];
    uint2 u0 = Pu2[(size_t)e0.x * 10 + lc];
    uint2 u1 = Pu2[(size_t)e1.x * 10 + lc];
    uint2 u2 = Pu2[(size_t)e2.x * 10 + lc];
    uint2 u3 = Pu2[(size_t)e3.x * 10 + lc];
    float n0 = __int_as_float(e0.y), n1 = __int_as_float(e1.y);
    float n2 = __int_as_float(e2.y), n3 = __int_as_float(e3.y);
    a0  += n0 * blo(u0.x); a1  += n0 * bhi(u0.x); a2  += n0 * blo(u0.y); a3  += n0 * bhi(u0.y);
    p0a += n1 * blo(u1.x); p1a += n1 * bhi(u1.x); p2a += n1 * blo(u1.y); p3a += n1 * bhi(u1.y);
    q0a += n2 * blo(u2.x); q1a += n2 * bhi(u2.x); q2a += n2 * blo(u2.y); q3a += n2 * bhi(u2.y);
    r0a += n3 * blo(u3.x); r1a += n3 * bhi(u3.x); r2a += n3 * blo(u3.y); r3a += n3 * bhi(u3.y);
  }
  for (; i < end; ++i) {
    int2 e0 = ep[i];
    uint2 u0 = Pu2[(size_t)e0.x * 10 + lc];
    float n0 = __int_as_float(e0.y);
    a0 += n0 * blo(u0.x); a1 += n0 * bhi(u0.x); a2 += n0 * blo(u0.y); a3 += n0 * bhi(u0.y);
  }

  float v0, v1, v2, v3;
  if (act) {
    float4 bb = ((const float4*)b2)[l];
    v0 = a0 + p0a + q0a + r0a + bb.x;
    v1 = a1 + p1a + q1a + r1a + bb.y;
    v2 = a2 + p2a + q2a + r2a + bb.z;
    v3 = a3 + p3a + q3a + r3a + bb.w;
  } else {
    v0 = v1 = v2 = v3 = -1e30f;
  }
  // log-softmax over 40 classes held by 10 lanes of this quarter (shuffles stay in-quarter)
  float m = fmaxf(fmaxf(v0, v1), fmaxf(v2, v3));
  #pragma unroll
  for (int off = 8; off > 0; off >>= 1) m = fmaxf(m, __shfl_xor(m, off, 64));
  float e = act ? (expf(v0 - m) + expf(v1 - m) + expf(v2 - m) + expf(v3 - m)) : 0.f;
  float s = e;
  #pragma unroll
  for (int off = 8; off > 0; off >>= 1) s += __shfl_xor(s, off, 64);
  float lse = m + logf(s);
  if (act) {
    float4 o = make_float4(v0 - lse, v1 - lse, v2 - lse, v3 - lse);
    ((float4*)(out + (size_t)d * N_CLS))[l] = o;
  }
}

// ---------------- launcher ----------------
extern "C" void kernel_launch(void* const* d_in, const int* in_sizes, int n_in,
                              void* d_out, int out_size, void* d_ws, size_t ws_size,
                              hipStream_t stream) {
  const float* x  = (const float*)d_in[0];
  const int*   ei = (const int*)d_in[1];
  const int*  src = ei;                       // edge_index[0]
  const int*  dst = ei + N_EDGES;             // edge_index[1]
  const float* W1 = (const float*)d_in[2];
  const float* b1 = (const float*)d_in[3];
  const float* W2 = (const float*)d_in[4];
  const float* b2 = (const float*)d_in[5];
  float* out = (float*)d_out;

  // workspace layout (all 16B-aligned). Pb aliases xb2 (dead after k_gather1).
  float* dinv    = (float*)d_ws;                            // 131072 f
  int*   cnt     = (int*)(dinv + 131072);                   // 131072 i
  int*   offsets = cnt + 131072;                            // 131072 i
  int*   cursor  = offsets + 131072;                        // 131072 i
  unsigned* flags = (unsigned*)(cursor + 131072);           // 1024 u
  int2*  epair   = (int2*)(flags + 1024);                   // 500000 int2 (pad to 524288)
  uint2* xb2     = (uint2*)(epair + 524288);                // 3.2M uint2 (25.6 MB)
  unsigned short* Pb = (unsigned short*)xb2;                // alias: 4M us (8 MB) — xb dead by then
  unsigned short* z1b = (unsigned short*)(xb2 + 3200000);   // 12.8M us (25.6 MB)
  unsigned short* W1F = z1b + (size_t)N_NODES * IN_DIM;     // 65536 us
  unsigned short* W2F = W1F + HID * IN_DIM;                 // 24576 us

  k_zero <<<(N_NODES + 255) / 256, 256, 0, stream>>>(cnt, flags);
  k_count_xbf<<<N_CNTB + N_XBFB, 256, 0, stream>>>(dst, cnt, x, xb2);
  k_scan_prep<<<N_SBLK + N_PREPB, 256, 0, stream>>>(cnt, flags, offsets, cursor, dinv, W1, W2, W1F, W2F);
  k_fill <<<N_CNTB, 256, 0, stream>>>(src, dst, dinv, cursor, epair);
  k_gather1<<<N_NODES / 8, 256, 0, stream>>>(xb2, epair, offsets, cnt, dinv, (uint2*)z1b);
  k_fused_mfma<<<(N_NODES + 63) / 64, 64, 0, stream>>>(z1b, W1F, b1, W2F, Pb);
  k_gather2_lsm<<<N_NODES / 16, 256, 0, stream>>>((const uint2*)Pb, epair, offsets, cnt, dinv, b2, out);
}

// Round 4
// 226.950 us; speedup vs baseline: 2.3048x; 1.0523x over previous
//
#include <hip/hip_runtime.h>
#include <cstdint>
#include <cstddef>

#define N_NODES 100000
#define N_EDGES 500000
#define IN_DIM  128
#define HID     512
#define N_CLS   40
#define N_SBLK  ((N_NODES + 255) / 256)   // 391 scan blocks
#define N_CNTB  ((N_EDGES + 255) / 256)   // 1954 count blocks
#define N_XBFB  12500                     // xbf blocks (3.2M float4)
#define N_G1B   12500                     // gather1 blocks (100000 / 8)
#define N_PREPB 352                       // W-prep blocks

typedef short bf16x8 __attribute__((ext_vector_type(8)));
typedef float f32x4 __attribute__((ext_vector_type(4)));

__device__ inline unsigned short f2bf(float f) {
  unsigned u = __float_as_uint(f);
  u = u + 0x7fffu + ((u >> 16) & 1u);          // RNE
  return (unsigned short)(u >> 16);
}
__device__ inline float blo(unsigned u) { return __uint_as_float(u << 16); }
__device__ inline float bhi(unsigned u) { return __uint_as_float(u & 0xffff0000u); }

// ---------------- CSR build ----------------
__global__ __launch_bounds__(256) void k_zero(int* __restrict__ cnt, unsigned* __restrict__ flags) {
  int i = blockIdx.x * 256 + threadIdx.x;
  if (i < N_NODES) cnt[i] = 0;
  if (i == 0) flags[0] = 0;                    // global segment allocator
}

// pure count; atomicAdd's return value IS the edge's rank within its dst segment.
__global__ __launch_bounds__(256) void k_count(const int* __restrict__ dst, int* __restrict__ cnt,
                                               int* __restrict__ rank) {
  int e = blockIdx.x * 256 + threadIdx.x;
  if (e < N_EDGES) rank[e] = atomicAdd(&cnt[dst[e]], 1);
}

// arrival-order scan: block base via ONE atomicAdd on a global allocator (order irrelevant —
// aggregation is an order-independent sum; consumers use offsets[d] + cnt[d] as segment end).
__global__ __launch_bounds__(256) void k_scan(const int* __restrict__ cnt, unsigned* __restrict__ flags,
                                              int* __restrict__ offsets, float* __restrict__ dinv) {
  __shared__ int s[256];
  __shared__ int base_sh;
  int b = blockIdx.x;
  int i = b * 256 + threadIdx.x;
  int v = (i < N_NODES) ? cnt[i] : 0;
  s[threadIdx.x] = v;
  __syncthreads();
  #pragma unroll
  for (int off = 1; off < 256; off <<= 1) {
    int t = (threadIdx.x >= off) ? s[threadIdx.x - off] : 0;
    __syncthreads();
    s[threadIdx.x] += t;
    __syncthreads();
  }
  int incl = s[threadIdx.x];
  if (threadIdx.x == 0)
    base_sh = (int)atomicAdd(&flags[0], (unsigned)s[255]);   // arrival-order base
  __syncthreads();
  if (i < N_NODES) {
    int excl = base_sh + incl - v;
    offsets[i] = excl;
    dinv[i]    = rsqrtf((float)(v + 1));       // +1 self-loop
  }
}

// atomic-free fill (pos = offsets[d] + rank[e]) fused with x->bf16 conversion
// (xbf output is consumed by the NEXT kernel — filler sits adjacent to its consumer).
__global__ __launch_bounds__(256) void k_fill_xbf(const int* __restrict__ src, const int* __restrict__ dst,
                                                  const int* __restrict__ rank, const int* __restrict__ offsets,
                                                  const float* __restrict__ dinv, int2* __restrict__ epair,
                                                  const float* __restrict__ x, uint2* __restrict__ xb2) {
  int b = blockIdx.x;
  if (b < N_CNTB) {
    int e = b * 256 + threadIdx.x;
    if (e >= N_EDGES) return;
    int s = src[e], d = dst[e];
    int pos = offsets[d] + rank[e];
    float nrm = dinv[s] * dinv[d];
    epair[pos] = make_int2(s, __float_as_int(nrm));
  } else {
    int t = (b - N_CNTB) * 256 + threadIdx.x;  // 3.2M exact
    float4 v = ((const float4*)x)[t];
    uint2 o;
    o.x = (unsigned)f2bf(v.x) | ((unsigned)f2bf(v.y) << 16);
    o.y = (unsigned)f2bf(v.z) | ((unsigned)f2bf(v.w) << 16);
    xb2[t] = o;
  }
}

// ---------------- layer-1 aggregation (gather, bf16): Z1 = Ahat @ X ----------------
// blocks [0,N_G1B): ONE node per 32-lane half (row = 32 x uint2 = 256B); 2 nodes/wave;
// 4-way unroll => 8 concurrent row chains per wave. Segment end = offsets[d] + cnt[d].
// blocks beyond: W1F/W2F prep (consumed by the NEXT kernel, k_fused_mfma).
__global__ __launch_bounds__(256) void k_gather1(const uint2* __restrict__ xb, const int2* __restrict__ ep,
                                                 const int* __restrict__ offsets, const int* __restrict__ cnt,
                                                 const float* __restrict__ dinv, uint2* __restrict__ z1,
                                                 const float* __restrict__ W1, const float* __restrict__ W2,
                                                 unsigned short* __restrict__ W1F, unsigned short* __restrict__ W2F) {
  int b = blockIdx.x;
  if (b >= N_G1B) {
    int t = (b - N_G1B) * 256 + threadIdx.x;   // 90112 exact
    if (t < 65536) {
      int j = t & 7, lane = (t >> 3) & 63, rest = t >> 9;   // rest = c*4+s
      int s2 = rest & 3, c = rest >> 2;
      int k = s2 * 32 + (lane >> 4) * 8 + j;
      int n = c * 16 + (lane & 15);
      W1F[t] = f2bf(W1[k * HID + n]);
    } else {
      int u = t - 65536;                        // 24576
      int j = u & 7, lane = (u >> 3) & 63, rest = u >> 9;   // rest = gk*3+ct
      int ct = rest % 3, gk = rest / 3;
      int k = gk * 32 + (lane >> 4) * 8 + j;
      int col = ct * 16 + (lane & 15);
      W2F[u] = (col < N_CLS) ? f2bf(W2[k * N_CLS + col]) : (unsigned short)0;
    }
    return;
  }
  int lane = threadIdx.x & 63, h = lane >> 5, l = lane & 31;
  int d = b * 8 + (threadIdx.x >> 6) * 2 + h;   // 12500 blocks x 8 = 100000 exact
  int start = offsets[d], end = start + cnt[d];
  float dd = dinv[d], sl = dd * dd;
  uint2 su = xb[(size_t)d * 32 + l];
  float a0 = sl * blo(su.x), a1 = sl * bhi(su.x), a2 = sl * blo(su.y), a3 = sl * bhi(su.y);
  float p0a = 0.f, p1a = 0.f, p2a = 0.f, p3a = 0.f;
  float q0a = 0.f, q1a = 0.f, q2a = 0.f, q3a = 0.f;
  float r0a = 0.f, r1a = 0.f, r2a = 0.f, r3a = 0.f;

  int i = start;
  for (; i + 3 < end; i += 4) {
    int2 e0 = ep[i], e1 = ep[i + 1], e2 = ep[i + 2], e3 = ep[i + 3];
    uint2 r0 = xb[(size_t)e0.x * 32 + l];
    uint2 r1 = xb[(size_t)e1.x * 32 + l];
    uint2 r2 = xb[(size_t)e2.x * 32 + l];
    uint2 r3 = xb[(size_t)e3.x * 32 + l];
    float n0 = __int_as_float(e0.y), n1 = __int_as_float(e1.y);
    float n2 = __int_as_float(e2.y), n3 = __int_as_float(e3.y);
    a0  += n0 * blo(r0.x); a1  += n0 * bhi(r0.x); a2  += n0 * blo(r0.y); a3  += n0 * bhi(r0.y);
    p0a += n1 * blo(r1.x); p1a += n1 * bhi(r1.x); p2a += n1 * blo(r1.y); p3a += n1 * bhi(r1.y);
    q0a += n2 * blo(r2.x); q1a += n2 * bhi(r2.x); q2a += n2 * blo(r2.y); q3a += n2 * bhi(r2.y);
    r0a += n3 * blo(r3.x); r1a += n3 * bhi(r3.x); r2a += n3 * blo(r3.y); r3a += n3 * bhi(r3.y);
  }
  for (; i < end; ++i) {
    int2 e0 = ep[i];
    uint2 r0 = xb[(size_t)e0.x * 32 + l];
    float n0 = __int_as_float(e0.y);
    a0 += n0 * blo(r0.x); a1 += n0 * bhi(r0.x); a2 += n0 * blo(r0.y); a3 += n0 * bhi(r0.y);
  }
  a0 += p0a + q0a + r0a;
  a1 += p1a + q1a + r1a;
  a2 += p2a + q2a + r2a;
  a3 += p3a + q3a + r3a;
  uint2 o;
  o.x = (unsigned)f2bf(a0) | ((unsigned)f2bf(a1) << 16);
  o.y = (unsigned)f2bf(a2) | ((unsigned)f2bf(a3) << 16);
  z1[(size_t)d * 32 + l] = o;
}

// ---------------- fused GEMM1+bias+relu+GEMM2 via bf16 MFMA ----------------
// 1 wave per block, 64 rows (4 m-tiles): every B-fragment load feeds 16 MFMAs.
// Epilogue: pair-swap (shfl_xor 1) + v_cvt_pk_bf16_f32 -> b32 LDS stores.
#define HS_STRIDE 56   // ushorts; 112B rows: 16B-aligned b128 reads, worst 2-way conflict = free
__global__ __launch_bounds__(64) void k_fused_mfma(const unsigned short* __restrict__ z1b,
                                                   const unsigned short* __restrict__ W1F,
                                                   const float* __restrict__ b1,
                                                   const unsigned short* __restrict__ W2F,
                                                   unsigned short* __restrict__ Pb) {
  __shared__ unsigned short Hs[64 * HS_STRIDE];   // 7168 B
  const int lane = threadIdx.x;                   // 0..63 (one wave)
  const int c16  = lane & 15, quad = lane >> 4;
  const int odd  = c16 & 1;
  const int mbase = blockIdx.x * 64;              // 1563 blocks x 64 >= 100000

  bf16x8 afrag[4][4];
  #pragma unroll
  for (int t = 0; t < 4; ++t) {
    int mrow = mbase + t * 16 + c16;
    int meff = (mrow < N_NODES) ? mrow : 0;
    const bf16x8* arow = (const bf16x8*)(z1b + (size_t)meff * IN_DIM + quad * 8);
    afrag[t][0] = arow[0];
    afrag[t][1] = arow[4];     // +32 ushorts
    afrag[t][2] = arow[8];
    afrag[t][3] = arow[12];
  }

  f32x4 pacc[4][3];
  #pragma unroll
  for (int t = 0; t < 4; ++t)
    #pragma unroll
    for (int ct = 0; ct < 3; ++ct) pacc[t][ct] = (f32x4){0.f, 0.f, 0.f, 0.f};

  const bf16x8* w1f = (const bf16x8*)W1F;
  const bf16x8* w2f = (const bf16x8*)W2F;
  unsigned short* hs = Hs;

  for (int g = 0; g < 16; ++g) {               // 32 H-cols per group
    #pragma unroll
    for (int nt = 0; nt < 2; ++nt) {
      int c = g * 2 + nt;                      // 16-col chunk
      bf16x8 bp0 = w1f[(c * 4 + 0) * 64 + lane];   // coalesced
      bf16x8 bp1 = w1f[(c * 4 + 1) * 64 + lane];
      bf16x8 bp2 = w1f[(c * 4 + 2) * 64 + lane];
      bf16x8 bp3 = w1f[(c * 4 + 3) * 64 + lane];
      f32x4 h[4];
      #pragma unroll
      for (int t = 0; t < 4; ++t) h[t] = (f32x4){0.f, 0.f, 0.f, 0.f};
      #pragma unroll
      for (int t = 0; t < 4; ++t) h[t] = __builtin_amdgcn_mfma_f32_16x16x32_bf16(afrag[t][0], bp0, h[t], 0, 0, 0);
      #pragma unroll
      for (int t = 0; t < 4; ++t) h[t] = __builtin_amdgcn_mfma_f32_16x16x32_bf16(afrag[t][1], bp1, h[t], 0, 0, 0);
      #pragma unroll
      for (int t = 0; t < 4; ++t) h[t] = __builtin_amdgcn_mfma_f32_16x16x32_bf16(afrag[t][2], bp2, h[t], 0, 0, 0);
      #pragma unroll
      for (int t = 0; t < 4; ++t) h[t] = __builtin_amdgcn_mfma_f32_16x16x32_bf16(afrag[t][3], bp3, h[t], 0, 0, 0);
      float bias = b1[c * 16 + c16];
      int colb = nt * 16 + (c16 & ~1);
      int rb0  = quad * 4 + (odd ? 2 : 0);
      #pragma unroll
      for (int t = 0; t < 4; ++t) {
        // C layout: lane (c16, quad) reg r -> (row = quad*4+r, col = c16)
        float v0 = fmaxf(h[t][0] + bias, 0.f);
        float v1 = fmaxf(h[t][1] + bias, 0.f);
        float v2 = fmaxf(h[t][2] + bias, 0.f);
        float v3 = fmaxf(h[t][3] + bias, 0.f);
        float o0 = __shfl_xor(v0, 1, 64);
        float o1 = __shfl_xor(v1, 1, 64);
        float o2 = __shfl_xor(v2, 1, 64);
        float o3 = __shfl_xor(v3, 1, 64);
        // even lane stores rows quad*4+{0,1}; odd lane rows quad*4+{2,3}; each b32 = (even col, odd col)
        float lo0 = odd ? o2 : v0, hi0 = odd ? v2 : o0;
        float lo1 = odd ? o3 : v1, hi1 = odd ? v3 : o1;
        unsigned p0, p1;
        asm("v_cvt_pk_bf16_f32 %0, %1, %2" : "=v"(p0) : "v"(lo0), "v"(hi0));   // RNE, == f2bf pair
        asm("v_cvt_pk_bf16_f32 %0, %1, %2" : "=v"(p1) : "v"(lo1), "v"(hi1));
        *(unsigned*)(hs + (t * 16 + rb0    ) * HS_STRIDE + colb) = p0;
        *(unsigned*)(hs + (t * 16 + rb0 + 1) * HS_STRIDE + colb) = p1;
      }
    }
    bf16x8 hf[4];
    #pragma unroll
    for (int t = 0; t < 4; ++t)
      hf[t] = *(const bf16x8*)(hs + (t * 16 + c16) * HS_STRIDE + quad * 8);
    #pragma unroll
    for (int ct = 0; ct < 3; ++ct) {
      bf16x8 bf = w2f[(g * 3 + ct) * 64 + lane];   // coalesced
      #pragma unroll
      for (int t = 0; t < 4; ++t)
        pacc[t][ct] = __builtin_amdgcn_mfma_f32_16x16x32_bf16(hf[t], bf, pacc[t][ct], 0, 0, 0);
    }
  }

  #pragma unroll
  for (int t = 0; t < 4; ++t) {
    int mrow0 = mbase + t * 16 + quad * 4;
    #pragma unroll
    for (int ct = 0; ct < 3; ++ct) {
      int col = ct * 16 + c16;
      if (col < N_CLS) {
        #pragma unroll
        for (int r = 0; r < 4; ++r) {
          int m = mrow0 + r;
          if (m < N_NODES) Pb[(size_t)m * N_CLS + col] = f2bf(pacc[t][ct][r]);
        }
      }
    }
  }
}

// ---------------- layer-2 aggregation (gather bf16, 40-dim) + bias + log_softmax ----------------
// ONE node per 16-lane quarter; 10 active lanes x uint2 (4 packed classes) = 80B row.
// 4 nodes/wave, 4-way unroll => 16 concurrent Pb-row chains per wave. float4 output.
// Segment end = offsets[d] + cnt[d].
__global__ __launch_bounds__(256) void k_gather2_lsm(const uint2* __restrict__ Pu2,
                                                     const int2* __restrict__ ep,
                                                     const int* __restrict__ offsets, const int* __restrict__ cnt,
                                                     const float* __restrict__ dinv, const float* __restrict__ b2,
                                                     float* __restrict__ out) {
  int lane = threadIdx.x & 63, q = lane >> 4, l = lane & 15;
  int d = blockIdx.x * 16 + (threadIdx.x >> 6) * 4 + q;   // 6250 blocks x 16 = 100000 exact
  bool act = l < 10;
  int lc = act ? l : 0;
  int start = offsets[d], end = start + cnt[d];
  float dd = dinv[d], sl = dd * dd;

  uint2 su = Pu2[(size_t)d * 10 + lc];
  float a0 = sl * blo(su.x), a1 = sl * bhi(su.x), a2 = sl * blo(su.y), a3 = sl * bhi(su.y);
  float p0a = 0.f, p1a = 0.f, p2a = 0.f, p3a = 0.f;
  float q0a = 0.f, q1a = 0.f, q2a = 0.f, q3a = 0.f;
  float r0a = 0.f, r1a = 0.f, r2a = 0.f, r3a = 0.f;

  int i = start;
  for (; i + 3 < end; i += 4) {
    int2 e0 = ep[i], e1 = ep[i + 1], e2 = ep[i + 2], e3 = ep[i + 3];
    uint2 u0 = Pu2[(size_t)e0.x * 10 + lc];
    uint2 u1 = Pu2[(size_t)e1.x * 10 + lc];
    uint2 u2 = Pu2[(size_t)e2.x * 10 + lc];
    uint2 u3 = Pu2[(size_t)e3.x * 10 + lc];
    float n0 = __int_as_float(e0.y), n1 = __int_as_float(e1.y);
    float n2 = __int_as_float(e2.y), n3 = __int_as_float(e3.y);
    a0  += n0 * blo(u0.x); a1  += n0 * bhi(u0.x); a2  += n0 * blo(u0.y); a3  += n0 * bhi(u0.y);
    p0a += n1 * blo(u1.x); p1a += n1 * bhi(u1.x); p2a += n1 * blo(u1.y); p3a += n1 * bhi(u1.y);
    q0a += n2 * blo(u2.x); q1a += n2 * bhi(u2.x); q2a += n2 * blo(u2.y); q3a += n2 * bhi(u2.y);
    r0a += n3 * blo(u3.x); r1a += n3 * bhi(u3.x); r2a += n3 * blo(u3.y); r3a += n3 * bhi(u3.y);
  }
  for (; i < end; ++i) {
    int2 e0 = ep[i];
    uint2 u0 = Pu2[(size_t)e0.x * 10 + lc];
    float n0 = __int_as_float(e0.y);
    a0 += n0 * blo(u0.x); a1 += n0 * bhi(u0.x); a2 += n0 * blo(u0.y); a3 += n0 * bhi(u0.y);
  }

  float v0, v1, v2, v3;
  if (act) {
    float4 bb = ((const float4*)b2)[l];
    v0 = a0 + p0a + q0a + r0a + bb.x;
    v1 = a1 + p1a + q1a + r1a + bb.y;
    v2 = a2 + p2a + q2a + r2a + bb.z;
    v3 = a3 + p3a + q3a + r3a + bb.w;
  } else {
    v0 = v1 = v2 = v3 = -1e30f;
  }
  // log-softmax over 40 classes held by 10 lanes of this quarter (shuffles stay in-quarter)
  float m = fmaxf(fmaxf(v0, v1), fmaxf(v2, v3));
  #pragma unroll
  for (int off = 8; off > 0; off >>= 1) m = fmaxf(m, __shfl_xor(m, off, 64));
  float e = act ? (expf(v0 - m) + expf(v1 - m) + expf(v2 - m) + expf(v3 - m)) : 0.f;
  float s = e;
  #pragma unroll
  for (int off = 8; off > 0; off >>= 1) s += __shfl_xor(s, off, 64);
  float lse = m + logf(s);
  if (act) {
    float4 o = make_float4(v0 - lse, v1 - lse, v2 - lse, v3 - lse);
    ((float4*)(out + (size_t)d * N_CLS))[l] = o;
  }
}

// ---------------- launcher ----------------
extern "C" void kernel_launch(void* const* d_in, const int* in_sizes, int n_in,
                              void* d_out, int out_size, void* d_ws, size_t ws_size,
                              hipStream_t stream) {
  const float* x  = (const float*)d_in[0];
  const int*   ei = (const int*)d_in[1];
  const int*  src = ei;                       // edge_index[0]
  const int*  dst = ei + N_EDGES;             // edge_index[1]
  const float* W1 = (const float*)d_in[2];
  const float* b1 = (const float*)d_in[3];
  const float* W2 = (const float*)d_in[4];
  const float* b2 = (const float*)d_in[5];
  float* out = (float*)d_out;

  // workspace layout (all 16B-aligned). Pb aliases xb2 (dead after k_gather1).
  float* dinv    = (float*)d_ws;                            // 131072 f
  int*   cnt     = (int*)(dinv + 131072);                   // 131072 i
  int*   offsets = cnt + 131072;                            // 131072 i
  unsigned* flags = (unsigned*)(offsets + 131072);          // 1024 u (only [0] used)
  int*   rank    = (int*)(flags + 1024);                    // 500000 i (pad to 524288)
  int2*  epair   = (int2*)(rank + 524288);                  // 500000 int2 (pad to 524288)
  uint2* xb2     = (uint2*)(epair + 524288);                // 3.2M uint2 (25.6 MB)
  unsigned short* Pb = (unsigned short*)xb2;                // alias: 4M us (8 MB) — xb dead by then
  unsigned short* z1b = (unsigned short*)(xb2 + 3200000);   // 12.8M us (25.6 MB)
  unsigned short* W1F = z1b + (size_t)N_NODES * IN_DIM;     // 65536 us
  unsigned short* W2F = W1F + HID * IN_DIM;                 // 24576 us

  k_zero    <<<N_SBLK, 256, 0, stream>>>(cnt, flags);
  k_count   <<<N_CNTB, 256, 0, stream>>>(dst, cnt, rank);
  k_scan    <<<N_SBLK, 256, 0, stream>>>(cnt, flags, offsets, dinv);
  k_fill_xbf<<<N_CNTB + N_XBFB, 256, 0, stream>>>(src, dst, rank, offsets, dinv, epair, x, xb2);
  k_gather1 <<<N_G1B + N_PREPB, 256, 0, stream>>>(xb2, epair, offsets, cnt, dinv, (uint2*)z1b,
                                                  W1, W2, W1F, W2F);
  k_fused_mfma<<<(N_NODES + 63) / 64, 64, 0, stream>>>(z1b, W1F, b1, W2F, Pb);
  k_gather2_lsm<<<N_NODES / 16, 256, 0, stream>>>((const uint2*)Pb, epair, offsets, cnt, dinv, b2, out);
}